// Round 1
// baseline (312.117 us; speedup 1.0000x reference)
//
#include <hip/hip_runtime.h>

typedef __bf16 bf16x8 __attribute__((ext_vector_type(8)));
typedef __bf16 bf16x4 __attribute__((ext_vector_type(4)));
typedef float  f32x4  __attribute__((ext_vector_type(4)));

#define GLDS16(g, l) __builtin_amdgcn_global_load_lds( \
    (const __attribute__((address_space(1))) void*)(g), \
    (__attribute__((address_space(3))) void*)(l), 16, 0, 0)

// ---------------- graph prep ----------------

__global__ void count_kernel(const int* __restrict__ dst, int* __restrict__ cnt, int E) {
  int idx = blockIdx.x * blockDim.x + threadIdx.x;
  int stride = gridDim.x * blockDim.x;
  for (int e = idx; e < E; e += stride) atomicAdd(&cnt[dst[e]], 1);
}

__global__ void dinv_kernel(const int* __restrict__ cnt, float* __restrict__ dinv, int n) {
  int i = blockIdx.x * blockDim.x + threadIdx.x;
  if (i < n) dinv[i] = rsqrtf((float)cnt[i] + 1.0f);
}

__global__ __launch_bounds__(1024) void scan_kernel(const int* __restrict__ cnt,
                                                    int* __restrict__ rowptr, int n) {
  __shared__ int part[1024];
  int t = threadIdx.x;
  int CH = (n + 1023) >> 10;          // elements per thread
  int base = t * CH;
  int s = 0;
  for (int j = 0; j < CH; j++) { int k = base + j; if (k < n) s += cnt[k]; }
  part[t] = s;
  __syncthreads();
  for (int off = 1; off < 1024; off <<= 1) {
    int v = (t >= off) ? part[t - off] : 0;
    __syncthreads();
    part[t] += v;
    __syncthreads();
  }
  int run = (t == 0) ? 0 : part[t - 1];
  for (int j = 0; j < CH; j++) { int k = base + j; if (k < n) { rowptr[k] = run; run += cnt[k]; } }
  if (t == 0) rowptr[n] = part[1023];
}

__global__ void fill_kernel(const int* __restrict__ src, const int* __restrict__ dst,
                            const int* __restrict__ rowptr, int* __restrict__ cur,
                            const float* __restrict__ dinv,
                            int* __restrict__ csr_src, float* __restrict__ csr_coef, int E) {
  int idx = blockIdx.x * blockDim.x + threadIdx.x;
  int stride = gridDim.x * blockDim.x;
  for (int e = idx; e < E; e += stride) {
    int s = src[e], d = dst[e];
    int slot = rowptr[d] + atomicAdd(&cur[d], 1);
    csr_src[slot] = s;
    csr_coef[slot] = dinv[s] * dinv[d];
  }
}

// ---------------- dtype prep ----------------

__global__ void f32_to_bf16_k(const float* __restrict__ in, __bf16* __restrict__ out, long n4) {
  long idx = (long)blockIdx.x * blockDim.x + threadIdx.x;
  long stride = (long)gridDim.x * blockDim.x;
  for (long i = idx; i < n4; i += stride) {
    float4 v = ((const float4*)in)[i];
    bf16x4 b;
    b[0] = (__bf16)v.x; b[1] = (__bf16)v.y; b[2] = (__bf16)v.z; b[3] = (__bf16)v.w;
    ((bf16x4*)out)[i] = b;
  }
}

// Wt[n*K + k] = W[k*Nw + n]  (transpose + convert)
__global__ void convT_kernel(const float* __restrict__ W, __bf16* __restrict__ Wt, int K, int Nw) {
  int id = blockIdx.x * blockDim.x + threadIdx.x;
  if (id >= K * Nw) return;
  int nn = id / K, kk = id % K;
  Wt[id] = (__bf16)W[kk * Nw + nn];
}

// Wct[n*K + k] = n<Z ? Wmu[k*Z+n] : Wlv[k*Z+n-Z]   (transposed concat head)
__global__ void packcat_kernel(const float* __restrict__ Wmu, const float* __restrict__ Wlv,
                               __bf16* __restrict__ Wct, int K, int Z) {
  int id = blockIdx.x * blockDim.x + threadIdx.x;
  if (id >= 2 * Z * K) return;
  int nn = id / K, kk = id % K;
  float v = (nn < Z) ? Wmu[kk * Z + nn] : Wlv[kk * Z + (nn - Z)];
  Wct[id] = (__bf16)v;
}

// ---------------- GEMM: C[M,N] = A[M,K] @ Bt[N,K]^T  (all bf16, f32 acc) ----------------
// 128x128 tile, BK=32, 4 waves in 2x2, each wave 64x64 (4x4 frags of 16x16x32)

__global__ __launch_bounds__(256) void gemm_bt(const __bf16* __restrict__ A,
                                               const __bf16* __restrict__ Bt,
                                               __bf16* __restrict__ C,
                                               int M, int N, int K) {
  __shared__ __align__(16) __bf16 sA[128 * 32];
  __shared__ __align__(16) __bf16 sB[128 * 32];
  const int tid = threadIdx.x;
  const int wave = tid >> 6, lane = tid & 63;
  const int m0 = blockIdx.x * 128, n0 = blockIdx.y * 128;
  const int wr = wave >> 1, wc = wave & 1;
  f32x4 acc[4][4] = {};
  const int lrow = lane >> 2;            // 0..15 within a 16-row chunk
  const int lkb  = (lane & 3) * 8;       // bf16 element offset within 32-elem row (16B granules)

  for (int k0 = 0; k0 < K; k0 += 32) {
    #pragma unroll
    for (int c2 = 0; c2 < 2; ++c2) {
      int chunk = wave * 2 + c2;         // 0..7, 16 rows each
      int row = chunk * 16 + lrow;
      int ga = m0 + row; if (ga >= M) ga = M - 1;       // clamp tail reads
      GLDS16(A  + (long)ga * K        + k0 + lkb, sA + chunk * 512);
      GLDS16(Bt + (long)(n0 + row) * K + k0 + lkb, sB + chunk * 512);
    }
    __syncthreads();
    bf16x8 af[4], bfr[4];
    const int fr = lane & 15, fk = (lane >> 4) * 8;
    #pragma unroll
    for (int mi = 0; mi < 4; mi++)
      af[mi] = *(const bf16x8*)(sA + (wr * 64 + mi * 16 + fr) * 32 + fk);
    #pragma unroll
    for (int ni = 0; ni < 4; ni++)
      bfr[ni] = *(const bf16x8*)(sB + (wc * 64 + ni * 16 + fr) * 32 + fk);
    #pragma unroll
    for (int mi = 0; mi < 4; mi++)
      #pragma unroll
      for (int ni = 0; ni < 4; ni++)
        acc[mi][ni] = __builtin_amdgcn_mfma_f32_16x16x32_bf16(af[mi], bfr[ni], acc[mi][ni], 0, 0, 0);
    __syncthreads();
  }

  const int crow0 = (lane >> 4) * 4, ccol = lane & 15;
  #pragma unroll
  for (int mi = 0; mi < 4; mi++)
    #pragma unroll
    for (int ni = 0; ni < 4; ni++)
      #pragma unroll
      for (int r = 0; r < 4; r++) {
        int row = m0 + wr * 64 + mi * 16 + crow0 + r;
        if (row < M)
          C[(long)row * N + n0 + wc * 64 + ni * 16 + ccol] = (__bf16)acc[mi][ni][r];
      }
}

// ---------------- propagation: out = agg + self*h + b, fused epilogues ----------------
// MODE 0: relu + L2-normalize -> bf16 hout
// MODE 1: relu -> bf16 hout
// MODE 2: (F=256 = mu||lv) -> mu, log_var, z into f32 zout

template<int EPL> struct VSel;
template<> struct VSel<8> { typedef bf16x8 T; };
template<> struct VSel<4> { typedef bf16x4 T; };

template<int EPL, int MODE>
__global__ __launch_bounds__(256) void prop_kernel(
    const __bf16* __restrict__ Cin, const int* __restrict__ rowptr,
    const int* __restrict__ csr_src, const float* __restrict__ csr_coef,
    const float* __restrict__ dinv, const float* __restrict__ bias,
    const float* __restrict__ bmu, const float* __restrict__ blv,
    const float* __restrict__ eps,
    __bf16* __restrict__ hout, float* __restrict__ zout, int n) {
  constexpr int F = EPL * 64;
  typedef typename VSel<EPL>::T VecT;
  const int wave = threadIdx.x >> 6, lane = threadIdx.x & 63;
  const int i = blockIdx.x * 4 + wave;
  if (i >= n) return;

  float acc[EPL];
  {
    const float di = dinv[i];
    const float sc = di * di;
    VecT v = *(const VecT*)(Cin + (size_t)i * F + lane * EPL);
    #pragma unroll
    for (int j = 0; j < EPL; j++) acc[j] = sc * (float)v[j];
  }
  const int e1 = rowptr[i + 1];
  for (int e = rowptr[i]; e < e1; ++e) {
    int s = csr_src[e];
    float c = csr_coef[e];
    VecT v = *(const VecT*)(Cin + (size_t)s * F + lane * EPL);
    #pragma unroll
    for (int j = 0; j < EPL; j++) acc[j] += c * (float)v[j];
  }

  if constexpr (MODE == 0 || MODE == 1) {
    float ss = 0.f;
    #pragma unroll
    for (int j = 0; j < EPL; j++) {
      acc[j] += bias[lane * EPL + j];
      acc[j] = fmaxf(acc[j], 0.f);
      ss += acc[j] * acc[j];
    }
    float scale = 1.f;
    if constexpr (MODE == 0) {
      #pragma unroll
      for (int off = 32; off > 0; off >>= 1) ss += __shfl_xor(ss, off);
      scale = 1.f / fmaxf(sqrtf(ss), 1e-12f);
    }
    VecT o;
    #pragma unroll
    for (int j = 0; j < EPL; j++) o[j] = (__bf16)(acc[j] * scale);
    *(VecT*)(hout + (size_t)i * F + lane * EPL) = o;
  } else {
    const bool ismu = lane < 32;
    const int cb4 = (ismu ? lane : lane - 32) * 4;
    float v[4];
    #pragma unroll
    for (int j = 0; j < 4; j++) v[j] = acc[j] + (ismu ? bmu[cb4 + j] : blv[cb4 + j]);
    const size_t NZ = (size_t)n * 128;
    float* dstp = ismu ? (zout + NZ + (size_t)i * 128 + cb4)
                       : (zout + 2 * NZ + (size_t)i * 128 + cb4);
    float4 st; st.x = v[0]; st.y = v[1]; st.z = v[2]; st.w = v[3];
    *(float4*)dstp = st;
    float ov[4];
    #pragma unroll
    for (int j = 0; j < 4; j++) ov[j] = __shfl_xor(v[j], 32);
    if (ismu) {
      float4 ev = *(const float4*)(eps + (size_t)i * 128 + cb4);
      float4 zs;
      zs.x = v[0] + ev.x * expf(0.5f * ov[0]);
      zs.y = v[1] + ev.y * expf(0.5f * ov[1]);
      zs.z = v[2] + ev.z * expf(0.5f * ov[2]);
      zs.w = v[3] + ev.w * expf(0.5f * ov[3]);
      *(float4*)(zout + (size_t)i * 128 + cb4) = zs;
    }
  }
}

// ---------------- launch ----------------

extern "C" void kernel_launch(void* const* d_in, const int* in_sizes, int n_in,
                              void* d_out, int out_size, void* d_ws, size_t ws_size,
                              hipStream_t stream) {
  const float* x   = (const float*)d_in[0];
  const int*   ei  = (const int*)d_in[1];
  const float* eps = (const float*)d_in[2];
  const float* W1  = (const float*)d_in[3];
  const float* b1  = (const float*)d_in[4];
  const float* W2  = (const float*)d_in[5];
  const float* b2  = (const float*)d_in[6];
  const float* Wmu = (const float*)d_in[7];
  const float* bmu = (const float*)d_in[8];
  const float* Wlv = (const float*)d_in[9];
  const float* blv = (const float*)d_in[10];
  float* out = (float*)d_out;

  const int N = 20000, E = 320000, D = 512, H = 512, Z = 128;
  const int* src = ei;
  const int* dst = ei + E;

  char* p = (char*)d_ws;
  auto alloc = [&](size_t bytes) { char* r = p; p += (bytes + 255) & ~(size_t)255; return r; };
  int*    cnt      = (int*)alloc((size_t)N * 4);
  int*    cur      = (int*)alloc((size_t)N * 4);
  int*    rowptr   = (int*)alloc((size_t)(N + 1) * 4);
  float*  dinv     = (float*)alloc((size_t)N * 4);
  int*    csr_src  = (int*)alloc((size_t)E * 4);
  float*  csr_coef = (float*)alloc((size_t)E * 4);
  __bf16* xb  = (__bf16*)alloc((size_t)N * D * 2);
  __bf16* hb  = (__bf16*)alloc((size_t)N * H * 2);
  __bf16* cb  = (__bf16*)alloc((size_t)N * H * 2);
  __bf16* w1t = (__bf16*)alloc((size_t)D * H * 2);
  __bf16* w2t = (__bf16*)alloc((size_t)H * H * 2);
  __bf16* wct = (__bf16*)alloc((size_t)2 * Z * H * 2);

  hipMemsetAsync(cnt, 0, (size_t)N * 4, stream);
  hipMemsetAsync(cur, 0, (size_t)N * 4, stream);

  count_kernel<<<1250, 256, 0, stream>>>(dst, cnt, E);
  dinv_kernel<<<(N + 255) / 256, 256, 0, stream>>>(cnt, dinv, N);
  scan_kernel<<<1, 1024, 0, stream>>>(cnt, rowptr, N);
  fill_kernel<<<1250, 256, 0, stream>>>(src, dst, rowptr, cur, dinv, csr_src, csr_coef, E);

  f32_to_bf16_k<<<4096, 256, 0, stream>>>(x, xb, (long)N * D / 4);
  convT_kernel<<<(D * H + 255) / 256, 256, 0, stream>>>(W1, w1t, D, H);
  convT_kernel<<<(H * H + 255) / 256, 256, 0, stream>>>(W2, w2t, H, H);
  packcat_kernel<<<(2 * Z * H + 255) / 256, 256, 0, stream>>>(Wmu, Wlv, wct, H, Z);

  // layer 1
  gemm_bt<<<dim3((N + 127) / 128, H / 128), 256, 0, stream>>>(xb, w1t, cb, N, H, D);
  prop_kernel<8, 0><<<(N + 3) / 4, 256, 0, stream>>>(cb, rowptr, csr_src, csr_coef, dinv,
                                                     b1, nullptr, nullptr, nullptr, hb, nullptr, N);
  // layer 2
  gemm_bt<<<dim3((N + 127) / 128, H / 128), 256, 0, stream>>>(hb, w2t, cb, N, H, H);
  prop_kernel<8, 1><<<(N + 3) / 4, 256, 0, stream>>>(cb, rowptr, csr_src, csr_coef, dinv,
                                                     b2, nullptr, nullptr, nullptr, xb, nullptr, N);
  // heads (mu || lv) + reparameterize
  gemm_bt<<<dim3((N + 127) / 128, (2 * Z) / 128), 256, 0, stream>>>(xb, wct, cb, N, 2 * Z, H);
  prop_kernel<4, 2><<<(N + 3) / 4, 256, 0, stream>>>(cb, rowptr, csr_src, csr_coef, dinv,
                                                     nullptr, bmu, blv, eps, nullptr, out, N);
}

// Round 2
// 273.513 us; speedup vs baseline: 1.1411x; 1.1411x over previous
//
#include <hip/hip_runtime.h>

typedef __bf16 bf16x8 __attribute__((ext_vector_type(8)));
typedef __bf16 bf16x4 __attribute__((ext_vector_type(4)));
typedef float  f32x4  __attribute__((ext_vector_type(4)));

#define GLDS16(g, l) __builtin_amdgcn_global_load_lds( \
    (const __attribute__((address_space(1))) void*)(g), \
    (__attribute__((address_space(3))) void*)(l), 16, 0, 0)

// ---------------- graph prep ----------------

__global__ void count_kernel(const int* __restrict__ dst, int* __restrict__ cnt, int E) {
  int idx = blockIdx.x * blockDim.x + threadIdx.x;
  int stride = gridDim.x * blockDim.x;
  for (int e = idx; e < E; e += stride) atomicAdd(&cnt[dst[e]], 1);
}

__global__ void dinv_kernel(const int* __restrict__ cnt, float* __restrict__ dinv, int n) {
  int i = blockIdx.x * blockDim.x + threadIdx.x;
  if (i < n) dinv[i] = rsqrtf((float)cnt[i] + 1.0f);
}

__global__ __launch_bounds__(1024) void scan_kernel(const int* __restrict__ cnt,
                                                    int* __restrict__ rowptr, int n) {
  __shared__ int part[1024];
  int t = threadIdx.x;
  int CH = (n + 1023) >> 10;          // elements per thread
  int base = t * CH;
  int s = 0;
  for (int j = 0; j < CH; j++) { int k = base + j; if (k < n) s += cnt[k]; }
  part[t] = s;
  __syncthreads();
  for (int off = 1; off < 1024; off <<= 1) {
    int v = (t >= off) ? part[t - off] : 0;
    __syncthreads();
    part[t] += v;
    __syncthreads();
  }
  int run = (t == 0) ? 0 : part[t - 1];
  for (int j = 0; j < CH; j++) { int k = base + j; if (k < n) { rowptr[k] = run; run += cnt[k]; } }
  if (t == 0) rowptr[n] = part[1023];
}

__global__ void fill_kernel(const int* __restrict__ src, const int* __restrict__ dst,
                            const int* __restrict__ rowptr, int* __restrict__ cur,
                            const float* __restrict__ dinv,
                            int* __restrict__ csr_src, float* __restrict__ csr_coef, int E) {
  int idx = blockIdx.x * blockDim.x + threadIdx.x;
  int stride = gridDim.x * blockDim.x;
  for (int e = idx; e < E; e += stride) {
    int s = src[e], d = dst[e];
    int slot = rowptr[d] + atomicAdd(&cur[d], 1);
    csr_src[slot] = s;
    csr_coef[slot] = dinv[s] * dinv[d];
  }
}

// ---------------- dtype prep ----------------

__global__ void f32_to_bf16_k(const float* __restrict__ in, __bf16* __restrict__ out, long n4) {
  long idx = (long)blockIdx.x * blockDim.x + threadIdx.x;
  long stride = (long)gridDim.x * blockDim.x;
  for (long i = idx; i < n4; i += stride) {
    float4 v = ((const float4*)in)[i];
    bf16x4 b;
    b[0] = (__bf16)v.x; b[1] = (__bf16)v.y; b[2] = (__bf16)v.z; b[3] = (__bf16)v.w;
    ((bf16x4*)out)[i] = b;
  }
}

// Wt[n*K + k] = W[k*Nw + n]  (transpose + convert)
__global__ void convT_kernel(const float* __restrict__ W, __bf16* __restrict__ Wt, int K, int Nw) {
  int id = blockIdx.x * blockDim.x + threadIdx.x;
  if (id >= K * Nw) return;
  int nn = id / K, kk = id % K;
  Wt[id] = (__bf16)W[kk * Nw + nn];
}

// Wct[n*K + k] = n<Z ? Wmu[k*Z+n] : Wlv[k*Z+n-Z]   (transposed concat head)
__global__ void packcat_kernel(const float* __restrict__ Wmu, const float* __restrict__ Wlv,
                               __bf16* __restrict__ Wct, int K, int Z) {
  int id = blockIdx.x * blockDim.x + threadIdx.x;
  if (id >= 2 * Z * K) return;
  int nn = id / K, kk = id % K;
  float v = (nn < Z) ? Wmu[kk * Z + nn] : Wlv[kk * Z + (nn - Z)];
  Wct[id] = (__bf16)v;
}

// ---------------- GEMM: C[M,N] = A[M,K] @ Bt[N,K]^T  (all bf16, f32 acc) ----------------
// 128x128 tile, BK=64, 4 waves in 2x2, each wave 64x64 (4x4 frags of 16x16x32, 2 k-subtiles)
// LDS rows are 128B; XOR granule swizzle (g ^= row&7) -> 2-way (free) ds_read_b128.
// global_load_lds writes linearly, so the GLOBAL source granule is pre-permuted to match.

__global__ __launch_bounds__(256) void gemm_bt(const __bf16* __restrict__ A,
                                               const __bf16* __restrict__ Bt,
                                               __bf16* __restrict__ C,
                                               int M, int N, int K) {
  __shared__ __align__(16) __bf16 sA[128 * 64];
  __shared__ __align__(16) __bf16 sB[128 * 64];
  const int tid = threadIdx.x;
  const int wave = tid >> 6, lane = tid & 63;
  const int m0 = blockIdx.x * 128, n0 = blockIdx.y * 128;
  const int wr = wave >> 1, wc = wave & 1;
  f32x4 acc[4][4] = {};
  const int srow = lane >> 3;                 // row within 8-row chunk
  const int sg   = (lane & 7) ^ (srow & 7);   // pre-swizzled source granule (16B units)

  for (int k0 = 0; k0 < K; k0 += 64) {
    #pragma unroll
    for (int c = 0; c < 4; ++c) {
      int chunk = wave * 4 + c;               // 0..15, 8 rows each
      int row = chunk * 8 + srow;
      int ga = m0 + row; if (ga >= M) ga = M - 1;       // clamp tail reads
      GLDS16(A  + (long)ga * K         + k0 + sg * 8, sA + chunk * 512);
      GLDS16(Bt + (long)(n0 + row) * K + k0 + sg * 8, sB + chunk * 512);
    }
    __syncthreads();
    const int fr = lane & 15, gbase = lane >> 4;        // granule base 0..3
    bf16x8 af[4][2], bfr[4][2];
    #pragma unroll
    for (int mi = 0; mi < 4; mi++)
      #pragma unroll
      for (int ks = 0; ks < 2; ks++) {
        int row = wr * 64 + mi * 16 + fr;
        int gs = (ks * 4 + gbase) ^ (row & 7);
        af[mi][ks] = *(const bf16x8*)(sA + row * 64 + gs * 8);
      }
    #pragma unroll
    for (int ni = 0; ni < 4; ni++)
      #pragma unroll
      for (int ks = 0; ks < 2; ks++) {
        int row = wc * 64 + ni * 16 + fr;
        int gs = (ks * 4 + gbase) ^ (row & 7);
        bfr[ni][ks] = *(const bf16x8*)(sB + row * 64 + gs * 8);
      }
    #pragma unroll
    for (int mi = 0; mi < 4; mi++)
      #pragma unroll
      for (int ni = 0; ni < 4; ni++) {
        acc[mi][ni] = __builtin_amdgcn_mfma_f32_16x16x32_bf16(af[mi][0], bfr[ni][0], acc[mi][ni], 0, 0, 0);
        acc[mi][ni] = __builtin_amdgcn_mfma_f32_16x16x32_bf16(af[mi][1], bfr[ni][1], acc[mi][ni], 0, 0, 0);
      }
    __syncthreads();
  }

  const int crow0 = (lane >> 4) * 4, ccol = lane & 15;
  #pragma unroll
  for (int mi = 0; mi < 4; mi++)
    #pragma unroll
    for (int ni = 0; ni < 4; ni++)
      #pragma unroll
      for (int r = 0; r < 4; r++) {
        int row = m0 + wr * 64 + mi * 16 + crow0 + r;
        if (row < M)
          C[(long)row * N + n0 + wc * 64 + ni * 16 + ccol] = (__bf16)acc[mi][ni][r];
      }
}

// ---------------- propagation: out = agg + self*h + b, fused epilogues ----------------
// MODE 0: relu + L2-normalize -> bf16 hout
// MODE 1: relu -> bf16 hout
// MODE 2: (F=256 = mu||lv) -> mu, log_var, z into f32 zout
// Grid-stride over nodes, one wave per node, 4-deep batched edge gather for MLP.

template<int EPL> struct VSel;
template<> struct VSel<8> { typedef bf16x8 T; };
template<> struct VSel<4> { typedef bf16x4 T; };

template<int EPL, int MODE>
__global__ __launch_bounds__(512) void prop_kernel(
    const __bf16* __restrict__ Cin, const int* __restrict__ rowptr,
    const int* __restrict__ csr_src, const float* __restrict__ csr_coef,
    const float* __restrict__ dinv, const float* __restrict__ bias,
    const float* __restrict__ bmu, const float* __restrict__ blv,
    const float* __restrict__ eps,
    __bf16* __restrict__ hout, float* __restrict__ zout, int n) {
  constexpr int F = EPL * 64;
  constexpr int BAT = 4;
  typedef typename VSel<EPL>::T VecT;
  const int lane = threadIdx.x & 63;
  const int gw = blockIdx.x * (blockDim.x >> 6) + (threadIdx.x >> 6);
  const int nw = gridDim.x * (blockDim.x >> 6);

  for (int i = gw; i < n; i += nw) {
    float acc[EPL];
    {
      const float di = dinv[i];
      const float sc = di * di;
      VecT v = *(const VecT*)(Cin + (size_t)i * F + lane * EPL);
      #pragma unroll
      for (int j = 0; j < EPL; j++) acc[j] = sc * (float)v[j];
    }
    int e = rowptr[i];
    const int e1 = rowptr[i + 1];
    for (; e + BAT <= e1; e += BAT) {
      int s[BAT]; float c[BAT];
      #pragma unroll
      for (int q = 0; q < BAT; q++) { s[q] = csr_src[e + q]; c[q] = csr_coef[e + q]; }
      VecT v[BAT];
      #pragma unroll
      for (int q = 0; q < BAT; q++) v[q] = *(const VecT*)(Cin + (size_t)s[q] * F + lane * EPL);
      #pragma unroll
      for (int q = 0; q < BAT; q++)
        #pragma unroll
        for (int j = 0; j < EPL; j++) acc[j] += c[q] * (float)v[q][j];
    }
    for (; e < e1; ++e) {
      int s = csr_src[e];
      float c = csr_coef[e];
      VecT v = *(const VecT*)(Cin + (size_t)s * F + lane * EPL);
      #pragma unroll
      for (int j = 0; j < EPL; j++) acc[j] += c * (float)v[j];
    }

    if constexpr (MODE == 0 || MODE == 1) {
      float ss = 0.f;
      #pragma unroll
      for (int j = 0; j < EPL; j++) {
        acc[j] += bias[lane * EPL + j];
        acc[j] = fmaxf(acc[j], 0.f);
        ss += acc[j] * acc[j];
      }
      float scale = 1.f;
      if constexpr (MODE == 0) {
        #pragma unroll
        for (int off = 32; off > 0; off >>= 1) ss += __shfl_xor(ss, off);
        scale = 1.f / fmaxf(sqrtf(ss), 1e-12f);
      }
      VecT o;
      #pragma unroll
      for (int j = 0; j < EPL; j++) o[j] = (__bf16)(acc[j] * scale);
      *(VecT*)(hout + (size_t)i * F + lane * EPL) = o;
    } else {
      const bool ismu = lane < 32;
      const int cb4 = (ismu ? lane : lane - 32) * 4;
      float v[4];
      #pragma unroll
      for (int j = 0; j < 4; j++) v[j] = acc[j] + (ismu ? bmu[cb4 + j] : blv[cb4 + j]);
      const size_t NZ = (size_t)n * 128;
      float* dstp = ismu ? (zout + NZ + (size_t)i * 128 + cb4)
                         : (zout + 2 * NZ + (size_t)i * 128 + cb4);
      float4 st; st.x = v[0]; st.y = v[1]; st.z = v[2]; st.w = v[3];
      *(float4*)dstp = st;
      float ov[4];
      #pragma unroll
      for (int j = 0; j < 4; j++) ov[j] = __shfl_xor(v[j], 32);
      if (ismu) {
        float4 ev = *(const float4*)(eps + (size_t)i * 128 + cb4);
        float4 zs;
        zs.x = v[0] + ev.x * expf(0.5f * ov[0]);
        zs.y = v[1] + ev.y * expf(0.5f * ov[1]);
        zs.z = v[2] + ev.z * expf(0.5f * ov[2]);
        zs.w = v[3] + ev.w * expf(0.5f * ov[3]);
        *(float4*)(zout + (size_t)i * 128 + cb4) = zs;
      }
    }
  }
}

// ---------------- launch ----------------

extern "C" void kernel_launch(void* const* d_in, const int* in_sizes, int n_in,
                              void* d_out, int out_size, void* d_ws, size_t ws_size,
                              hipStream_t stream) {
  const float* x   = (const float*)d_in[0];
  const int*   ei  = (const int*)d_in[1];
  const float* eps = (const float*)d_in[2];
  const float* W1  = (const float*)d_in[3];
  const float* b1  = (const float*)d_in[4];
  const float* W2  = (const float*)d_in[5];
  const float* b2  = (const float*)d_in[6];
  const float* Wmu = (const float*)d_in[7];
  const float* bmu = (const float*)d_in[8];
  const float* Wlv = (const float*)d_in[9];
  const float* blv = (const float*)d_in[10];
  float* out = (float*)d_out;

  const int N = 20000, E = 320000, D = 512, H = 512, Z = 128;
  const int* src = ei;
  const int* dst = ei + E;

  char* p = (char*)d_ws;
  auto alloc = [&](size_t bytes) { char* r = p; p += (bytes + 255) & ~(size_t)255; return r; };
  int*    cnt      = (int*)alloc((size_t)N * 4);
  int*    cur      = (int*)alloc((size_t)N * 4);
  int*    rowptr   = (int*)alloc((size_t)(N + 1) * 4);
  float*  dinv     = (float*)alloc((size_t)N * 4);
  int*    csr_src  = (int*)alloc((size_t)E * 4);
  float*  csr_coef = (float*)alloc((size_t)E * 4);
  __bf16* xb  = (__bf16*)alloc((size_t)N * D * 2);
  __bf16* hb  = (__bf16*)alloc((size_t)N * H * 2);
  __bf16* cb  = (__bf16*)alloc((size_t)N * H * 2);
  __bf16* w1t = (__bf16*)alloc((size_t)D * H * 2);
  __bf16* w2t = (__bf16*)alloc((size_t)H * H * 2);
  __bf16* wct = (__bf16*)alloc((size_t)2 * Z * H * 2);

  hipMemsetAsync(cnt, 0, (size_t)N * 4, stream);
  hipMemsetAsync(cur, 0, (size_t)N * 4, stream);

  count_kernel<<<1250, 256, 0, stream>>>(dst, cnt, E);
  dinv_kernel<<<(N + 255) / 256, 256, 0, stream>>>(cnt, dinv, N);
  scan_kernel<<<1, 1024, 0, stream>>>(cnt, rowptr, N);
  fill_kernel<<<1250, 256, 0, stream>>>(src, dst, rowptr, cur, dinv, csr_src, csr_coef, E);

  f32_to_bf16_k<<<4096, 256, 0, stream>>>(x, xb, (long)N * D / 4);
  convT_kernel<<<(D * H + 255) / 256, 256, 0, stream>>>(W1, w1t, D, H);
  convT_kernel<<<(H * H + 255) / 256, 256, 0, stream>>>(W2, w2t, H, H);
  packcat_kernel<<<(2 * Z * H + 255) / 256, 256, 0, stream>>>(Wmu, Wlv, wct, H, Z);

  // layer 1
  gemm_bt<<<dim3((N + 127) / 128, H / 128), 256, 0, stream>>>(xb, w1t, cb, N, H, D);
  prop_kernel<8, 0><<<1024, 512, 0, stream>>>(cb, rowptr, csr_src, csr_coef, dinv,
                                              b1, nullptr, nullptr, nullptr, hb, nullptr, N);
  // layer 2
  gemm_bt<<<dim3((N + 127) / 128, H / 128), 256, 0, stream>>>(hb, w2t, cb, N, H, H);
  prop_kernel<8, 1><<<1024, 512, 0, stream>>>(cb, rowptr, csr_src, csr_coef, dinv,
                                              b2, nullptr, nullptr, nullptr, xb, nullptr, N);
  // heads (mu || lv) + reparameterize
  gemm_bt<<<dim3((N + 127) / 128, (2 * Z) / 128), 256, 0, stream>>>(xb, wct, cb, N, 2 * Z, H);
  prop_kernel<4, 2><<<1024, 512, 0, stream>>>(cb, rowptr, csr_src, csr_coef, dinv,
                                              nullptr, bmu, blv, eps, nullptr, out, N);
}